// Round 1
// baseline (256.617 us; speedup 1.0000x reference)
//
#include <hip/hip_runtime.h>
#include <hip/hip_fp16.h>
#include <math.h>

#define N_NODES 30000
#define E_EDGES 480000
#define VD      512
#define HID     32
#define BUCKET  3750   // rows per src-bucket: 3750 * 1KB = 3.75 MB < 4 MB per-XCD L2
#define K1_BLOCKS 512

// ws layout — BYTE-INTERVAL AUDIT (4-byte floats unless noted):
//   acc   floats [0, 30000)        = bytes [0, 120000)
//   deg   floats [30000, 60000)    = bytes [120000, 240000)
//   sarr  floats [60000, 90000)    = bytes [240000, 360000)
//   part  floats [90000, 92560)    = bytes [360000, 370240)   (K1_BLOCKS x 5)
//   inv   floats [92560, 122560)   = bytes [370240, 490240)   (fp32 fallback only)
//   nvis  bytes  [524288, 31244288)                            (fp16 rows, 1024 B/row)
//   -> no overlaps; total need 31.25 MB
#define ACC_OFF  0
#define DEG_OFF  30000
#define SARR_OFF 60000
#define PART_OFF 90000
#define INV_OFF  92560
#define NV_BYTE_OFF 524288u

__device__ inline float2 h2f(unsigned int u) {
    const __half2 h = *reinterpret_cast<const __half2*>(&u);
    return __half22float2(h);
}

typedef _Float16 h2vec __attribute__((ext_vector_type(2)));

// packed fp16 dot with f32 accumulate: v_dot2_f32_f16
__device__ inline float edot2(unsigned int a, unsigned int b, float c) {
#if __has_builtin(__builtin_amdgcn_fdot2)
    return __builtin_amdgcn_fdot2(*reinterpret_cast<const h2vec*>(&a),
                                  *reinterpret_cast<const h2vec*>(&b), c, false);
#else
    float2 u = h2f(a), v = h2f(b);
    return c + u.x * v.x + u.y * v.y;
#endif
}

// ================= K1: zero acc/deg + moment partials + normalize (R10-proven) =====
__global__ void __launch_bounds__(256) k1_prep(
        const float* __restrict__ x,
        const float* __restrict__ visual,
        float* __restrict__ ws, int fp16mode) {
    const int t      = threadIdx.x;
    const int gid    = blockIdx.x * blockDim.x + t;
    const int stride = gridDim.x * blockDim.x;
    const int lane   = t & 63;

    // --- zero acc + deg ---
    for (int i = gid; i < 2 * N_NODES; i += stride) ws[i] = 0.f;

    // --- per-block moment partials of x ---
    {
        __shared__ float red[4][5];
        float s0 = 0.f, s1 = 0.f, s00 = 0.f, s11 = 0.f, s01 = 0.f;
        for (int i = gid; i < N_NODES; i += stride) {
            float2 v = ((const float2*)x)[i];
            s0  += v.x;       s1  += v.y;
            s00 += v.x * v.x; s11 += v.y * v.y;
            s01 += v.x * v.y;
        }
        for (int o = 32; o; o >>= 1) {
            s0  += __shfl_xor(s0,  o, 64);
            s1  += __shfl_xor(s1,  o, 64);
            s00 += __shfl_xor(s00, o, 64);
            s11 += __shfl_xor(s11, o, 64);
            s01 += __shfl_xor(s01, o, 64);
        }
        int wv = t >> 6;
        if (lane == 0) {
            red[wv][0] = s0; red[wv][1] = s1; red[wv][2] = s00;
            red[wv][3] = s11; red[wv][4] = s01;
        }
        __syncthreads();
        if (t < 5) {
            ws[PART_OFF + blockIdx.x * 5 + t] =
                red[0][t] + red[1][t] + red[2][t] + red[3][t];
        }
    }

    // --- normalize visual rows (wave per node) ---
    ushort* nvis = (ushort*)((char*)ws + NV_BYTE_OFF);
    float*  inv  = ws + INV_OFF;
    int wave  = gid >> 6;
    int nwave = stride >> 6;
    for (int node = wave; node < N_NODES; node += nwave) {
        const float4* row = (const float4*)(visual + (size_t)node * VD);
        float4 a = row[lane];
        float4 b = row[lane + 64];
        float p = a.x*a.x + a.y*a.y + a.z*a.z + a.w*a.w
                + b.x*b.x + b.y*b.y + b.z*b.z + b.w*b.w;
        for (int o = 32; o; o >>= 1) p += __shfl_xor(p, o, 64);
        float r = 1.0f / fmaxf(sqrtf(p), 1e-8f);
        if (fp16mode) {
            __half2 p0 = __floats2half2_rn(a.x * r, a.y * r);
            __half2 p1 = __floats2half2_rn(a.z * r, a.w * r);
            __half2 p2 = __floats2half2_rn(b.x * r, b.y * r);
            __half2 p3 = __floats2half2_rn(b.z * r, b.w * r);
            uint2 q0, q1;
            q0.x = *(unsigned int*)&p0; q0.y = *(unsigned int*)&p1;
            q1.x = *(unsigned int*)&p2; q1.y = *(unsigned int*)&p3;
            uint2* orow = (uint2*)(nvis + (size_t)node * VD);
            orow[lane]      = q0;
            orow[lane + 64] = q1;
        } else if (lane == 0) {
            inv[node] = r;
        }
    }
}

// ================= K2: parallel fold of partials + BN scalars + sarr + deg hist ====
__global__ void __launch_bounds__(256) k2_sarr(
        const float* __restrict__ x,
        const int* __restrict__ ei,
        const float* __restrict__ w1, const float* __restrict__ b1,
        const float* __restrict__ gamma, const float* __restrict__ beta,
        const float* __restrict__ prelu_a,
        const float* __restrict__ w2, const float* __restrict__ b2,
        const float* __restrict__ wc, const float* __restrict__ wp,
        const float* __restrict__ ws_ro,
        float* __restrict__ sarr,
        float* __restrict__ deg) {
    __shared__ float red[4][5];
    __shared__ float s_S[5];
    __shared__ float s_scale[HID], s_shift[HID], s_u[HID], s_w1a[HID], s_w1b[HID];
    __shared__ float s_wpc[HID];
    __shared__ float s_sb;
    const float* part = ws_ro + PART_OFF;
    const int t    = threadIdx.x;
    const int lane = t & 63;

    {
        float S[5] = {0.f, 0.f, 0.f, 0.f, 0.f};
        for (int j = t; j < K1_BLOCKS; j += 256) {
            #pragma unroll
            for (int c = 0; c < 5; ++c) S[c] += part[j * 5 + c];
        }
        #pragma unroll
        for (int c = 0; c < 5; ++c)
            for (int o = 32; o; o >>= 1) S[c] += __shfl_xor(S[c], o, 64);
        int wv = t >> 6;
        if (lane == 0) {
            #pragma unroll
            for (int c = 0; c < 5; ++c) red[wv][c] = S[c];
        }
        __syncthreads();
        if (t < 5) s_S[t] = red[0][t] + red[1][t] + red[2][t] + red[3][t];
        __syncthreads();
    }

    if (t < HID) {
        float wpck = 0.f;
        for (int j = 0; j < HID; ++j) wpck += wp[j] * wc[j * HID + t];
        s_wpc[t] = wpck;
        const float invN = 1.0f / (float)N_NODES;
        float m0  = s_S[0] * invN, m1 = s_S[1] * invN;
        float v0  = fmaxf(s_S[2] * invN - m0 * m0, 0.f);
        float v1  = fmaxf(s_S[3] * invN - m1 * m1, 0.f);
        float c01 = s_S[4] * invN - m0 * m1;
        float a0 = w1[2 * t], a1 = w1[2 * t + 1];
        float mean = a0 * m0 + a1 * m1 + b1[t];
        float var  = fmaxf(a0 * a0 * v0 + a1 * a1 * v1 + 2.f * a0 * a1 * c01, 0.f);
        float rs    = 1.0f / sqrtf(var + 1e-5f);
        float scale = gamma[t] * rs;
        s_scale[t] = scale;
        s_shift[t] = beta[t] - mean * scale;
        s_w1a[t] = a0; s_w1b[t] = a1;
    }
    __syncthreads();
    if (t < HID) {
        float uu = 0.f;
        for (int k = 0; k < HID; ++k) uu += s_wpc[k] * w2[k * HID + t];
        s_u[t] = uu;
    }
    if (t == 0) {
        float sb = 0.f;
        for (int k = 0; k < HID; ++k) sb += s_wpc[k] * b2[k];
        s_sb = sb;
    }
    __syncthreads();
    const float aslope = prelu_a[0];
    const float sb = s_sb;
    for (int i = blockIdx.x * blockDim.x + t; i < N_NODES; i += gridDim.x * blockDim.x) {
        float2 xv = ((const float2*)x)[i];
        float sacc = sb;
        #pragma unroll
        for (int c = 0; c < HID; ++c) {
            float h  = s_w1a[c] * xv.x + s_w1b[c] * xv.y + b1[c];
            float tt = h * s_scale[c] + s_shift[c];
            tt = tt >= 0.f ? tt : aslope * tt;
            sacc += tt * s_u[c];
        }
        sarr[i] = sacc;
    }

    // --- deg histogram (moved out of K3: independent of edge weights) ---
    for (int e = blockIdx.x * blockDim.x + t; e < E_EDGES; e += gridDim.x * blockDim.x) {
        atomicAdd(&deg[ei[E_EDGES + e]], 1.0f);
    }
}

// ===== K3: src-bucketed skip-scan edge kernel, quarter-wave (16-lane) per edge =====
// 4 edges per wave-iteration in disjoint 16-lane groups:
//   - v_dot2_f32_f16 packed dot (no cvt chain)
//   - 4-level butterfly reduces all 4 edges simultaneously
//   - atomics issue concurrently from 4 group-leader lanes
//   - deg histogram removed (done in K2)
__global__ void __launch_bounds__(256) k3_edge16(const int* __restrict__ ei,
                                                 const float* __restrict__ ws_ro,
                                                 float* __restrict__ acc,
                                                 const float* __restrict__ sarr) {
    const char* nvb = (const char*)ws_ro + NV_BYTE_OFF;
    const int lane = threadIdx.x & 63;
    const int sub  = lane & 15;                            // lane within 16-group
    const int g    = lane >> 4;                            // edge-group 0..3
    const int r    = blockIdx.x & 7;                       // src-bucket residue -> XCD
    const int q    = (blockIdx.x >> 3) * (blockDim.x >> 6) + (threadIdx.x >> 6);
    const int nq   = (gridDim.x >> 3) * (blockDim.x >> 6);
    const int nchunk = E_EDGES >> 6;                       // 7500 (exact)

    for (int c = q; c < nchunk; c += nq) {
        int idx = (c << 6) + lane;
        int s = ei[idx];
        int d = ei[E_EDGES + idx];
        bool mine = (s / BUCKET == r);
        float mys = mine ? sarr[s] : 0.f;
        unsigned long long m = __ballot(mine);
        while (m) {
            // extract up to 4 set bits; inactive slots duplicate slot 0
            int j0 = __ffsll(m) - 1;  m &= m - 1;
            int cnt = 1;
            int j1 = j0, j2 = j0, j3 = j0;
            if (m) { j1 = __ffsll(m) - 1; m &= m - 1; cnt = 2; }
            if (m) { j2 = __ffsll(m) - 1; m &= m - 1; cnt = 3; }
            if (m) { j3 = __ffsll(m) - 1; m &= m - 1; cnt = 4; }

            // per-lane source-lane select: group g pulls edge j_g
            int jsel = (g == 0) ? j0 : (g == 1) ? j1 : (g == 2) ? j2 : j3;
            int   se = __shfl(s,   jsel, 64);
            int   de = __shfl(d,   jsel, 64);
            float sv = __shfl(mys, jsel, 64);

            // each 16-lane group reads its edge's two rows; per load instr a
            // group covers 256 contiguous bytes (perfect coalescing)
            const uint4* sa = (const uint4*)(nvb + ((size_t)se << 10)) + sub;
            const uint4* da = (const uint4*)(nvb + ((size_t)de << 10)) + sub;
            uint4 A0 = sa[0];
            uint4 B0 = da[0];
            uint4 A1 = sa[16];
            uint4 B1 = da[16];
            uint4 A2 = sa[32];
            uint4 B2 = da[32];
            uint4 A3 = sa[48];
            uint4 B3 = da[48];

            float p = 0.f;
            p = edot2(A0.x, B0.x, p);
            p = edot2(A0.y, B0.y, p);
            p = edot2(A0.z, B0.z, p);
            p = edot2(A0.w, B0.w, p);
            p = edot2(A1.x, B1.x, p);
            p = edot2(A1.y, B1.y, p);
            p = edot2(A1.z, B1.z, p);
            p = edot2(A1.w, B1.w, p);
            p = edot2(A2.x, B2.x, p);
            p = edot2(A2.y, B2.y, p);
            p = edot2(A2.z, B2.z, p);
            p = edot2(A2.w, B2.w, p);
            p = edot2(A3.x, B3.x, p);
            p = edot2(A3.y, B3.y, p);
            p = edot2(A3.z, B3.z, p);
            p = edot2(A3.w, B3.w, p);

            // 4-level butterfly inside each 16-lane group: reduces all 4
            // edges simultaneously (offsets 8,4,2,1 never cross a group)
            p += __shfl_xor(p, 8, 64);
            p += __shfl_xor(p, 4, 64);
            p += __shfl_xor(p, 2, 64);
            p += __shfl_xor(p, 1, 64);

            if (sub == 0 && g < cnt) {
                atomicAdd(&acc[de], p * sv);
            }
        }
    }
}

// fp32 fallback edge kernel (correctness path; deg handled in K2)
__global__ void __launch_bounds__(256) k3_edge32(const int* __restrict__ ei,
                                                 const float* __restrict__ visual,
                                                 const float* __restrict__ inv,
                                                 const float* __restrict__ sarr,
                                                 float* __restrict__ acc) {
    int wave  = (blockIdx.x * blockDim.x + threadIdx.x) >> 6;
    int lane  = threadIdx.x & 63;
    int nwave = (gridDim.x * blockDim.x) >> 6;
    for (int e = wave; e < E_EDGES; e += nwave) {
        int s = ei[e];
        int d = ei[E_EDGES + e];
        const float4* ra = (const float4*)(visual + (size_t)s * VD);
        const float4* rb = (const float4*)(visual + (size_t)d * VD);
        float4 a0 = ra[lane];
        float4 b0 = rb[lane];
        float4 a1 = ra[lane + 64];
        float4 b1 = rb[lane + 64];
        float p = a0.x*b0.x + a0.y*b0.y + a0.z*b0.z + a0.w*b0.w
                + a1.x*b1.x + a1.y*b1.y + a1.z*b1.z + a1.w*b1.w;
        for (int o = 32; o; o >>= 1) p += __shfl_xor(p, o, 64);
        if (lane == 0) {
            float w = p * inv[s] * inv[d];
            atomicAdd(&acc[d], w * sarr[s]);
        }
    }
}

// ================= K4: final =================
__global__ void k4_final(const float* __restrict__ acc, const float* __restrict__ deg,
                         const float* __restrict__ bc, const float* __restrict__ wp,
                         const float* __restrict__ bp, float* __restrict__ out, int n) {
    float K = bp[0];
    #pragma unroll
    for (int j = 0; j < HID; ++j) K += wp[j] * bc[j];
    for (int i = blockIdx.x * blockDim.x + threadIdx.x; i < n; i += gridDim.x * blockDim.x) {
        out[i] = acc[i] / fmaxf(deg[i], 1.0f) + K;
    }
}

extern "C" void kernel_launch(void* const* d_in, const int* in_sizes, int n_in,
                              void* d_out, int out_size, void* d_ws, size_t ws_size,
                              hipStream_t stream) {
    const float* x       = (const float*)d_in[0];
    const float* visual  = (const float*)d_in[1];
    const int*   ei      = (const int*)  d_in[2];
    const float* w1      = (const float*)d_in[3];
    const float* b1      = (const float*)d_in[4];
    const float* gamma   = (const float*)d_in[5];
    const float* beta    = (const float*)d_in[6];
    const float* prelu_a = (const float*)d_in[7];
    const float* w2      = (const float*)d_in[8];
    const float* b2      = (const float*)d_in[9];
    const float* wc      = (const float*)d_in[10];
    const float* bc      = (const float*)d_in[11];
    const float* wp      = (const float*)d_in[12];
    const float* bp      = (const float*)d_in[13];
    float* out = (float*)d_out;

    float* ws   = (float*)d_ws;
    float* acc  = ws + ACC_OFF;
    float* deg  = ws + DEG_OFF;
    float* sarr = ws + SARR_OFF;
    float* inv  = ws + INV_OFF;

    bool fp16ok = ws_size >= (size_t)NV_BYTE_OFF + (size_t)N_NODES * VD * 2;

    k1_prep<<<K1_BLOCKS, 256, 0, stream>>>(x, visual, ws, fp16ok ? 1 : 0);
    k2_sarr<<<256, 256, 0, stream>>>(x, ei, w1, b1, gamma, beta, prelu_a, w2, b2, wc, wp,
                                     ws, sarr, deg);
    if (fp16ok) {
        k3_edge16<<<4096, 256, 0, stream>>>(ei, ws, acc, sarr);
    } else {
        k3_edge32<<<4096, 256, 0, stream>>>(ei, visual, inv, sarr, acc);
    }
    k4_final<<<120, 256, 0, stream>>>(acc, deg, bc, wp, bp, out, N_NODES);
}

// Round 3
// 199.631 us; speedup vs baseline: 1.2855x; 1.2855x over previous
//
#include <hip/hip_runtime.h>
#include <hip/hip_fp16.h>
#include <math.h>

#define N_NODES 30000
#define E_EDGES 480000
#define VD      512
#define HID     32
#define BUCKET  3750   // rows per src-bucket; int8 rows: 3750 * 512B = 1.92 MB << 4 MB L2
#define K1_BLOCKS 512

// ws layout — BYTE-INTERVAL AUDIT (4-byte floats unless noted):
//   acc   floats [0, 30000)        = bytes [0, 120000)
//   deg   floats [30000, 60000)    = bytes [120000, 240000)
//   sarr  floats [60000, 90000)    = bytes [240000, 360000)   (holds qs[s]*sarr[s] in int8 mode)
//   part  floats [90000, 92560)    = bytes [360000, 370240)   (K1_BLOCKS x 5)
//   inv   floats [92560, 122560)   = bytes [370240, 490240)   (int8 mode: per-row qs; fp32 fallback: 1/norm)
//   nvis8 bytes  [524288, 15884288)                           (int8 rows, 512 B/row)
//   -> no overlaps; total need 15.9 MB
#define ACC_OFF  0
#define DEG_OFF  30000
#define SARR_OFF 60000
#define PART_OFF 90000
#define INV_OFF  92560
#define NV_BYTE_OFF 524288u

// packed int8 dot with i32 accumulate: v_dot4_i32_i8
__device__ inline int edot4(unsigned int a, unsigned int b, int c) {
#if __has_builtin(__builtin_amdgcn_sdot4)
    return __builtin_amdgcn_sdot4((int)a, (int)b, (int)c, false);
#else
    int r = c;
    r += (int)(signed char)(a)       * (int)(signed char)(b);
    r += (int)(signed char)(a >> 8)  * (int)(signed char)(b >> 8);
    r += (int)(signed char)(a >> 16) * (int)(signed char)(b >> 16);
    r += (int)(signed char)(a >> 24) * (int)(signed char)(b >> 24);
    return r;
#endif
}

__device__ inline unsigned int pack4i8(float x0, float x1, float x2, float x3, float sc) {
    int q0 = (int)rintf(x0 * sc);
    int q1 = (int)rintf(x1 * sc);
    int q2 = (int)rintf(x2 * sc);
    int q3 = (int)rintf(x3 * sc);
    return (unsigned int)(q0 & 255) | ((unsigned int)(q1 & 255) << 8) |
           ((unsigned int)(q2 & 255) << 16) | ((unsigned int)(q3 & 255) << 24);
}

// ================= K1: zero acc/deg + moment partials + normalize+quantize =====
__global__ void __launch_bounds__(256) k1_prep(
        const float* __restrict__ x,
        const float* __restrict__ visual,
        float* __restrict__ ws, int i8mode) {
    const int t      = threadIdx.x;
    const int gid    = blockIdx.x * blockDim.x + t;
    const int stride = gridDim.x * blockDim.x;
    const int lane   = t & 63;

    // --- zero acc + deg ---
    for (int i = gid; i < 2 * N_NODES; i += stride) ws[i] = 0.f;

    // --- per-block moment partials of x ---
    {
        __shared__ float red[4][5];
        float s0 = 0.f, s1 = 0.f, s00 = 0.f, s11 = 0.f, s01 = 0.f;
        for (int i = gid; i < N_NODES; i += stride) {
            float2 v = ((const float2*)x)[i];
            s0  += v.x;       s1  += v.y;
            s00 += v.x * v.x; s11 += v.y * v.y;
            s01 += v.x * v.y;
        }
        for (int o = 32; o; o >>= 1) {
            s0  += __shfl_xor(s0,  o, 64);
            s1  += __shfl_xor(s1,  o, 64);
            s00 += __shfl_xor(s00, o, 64);
            s11 += __shfl_xor(s11, o, 64);
            s01 += __shfl_xor(s01, o, 64);
        }
        int wv = t >> 6;
        if (lane == 0) {
            red[wv][0] = s0; red[wv][1] = s1; red[wv][2] = s00;
            red[wv][3] = s11; red[wv][4] = s01;
        }
        __syncthreads();
        if (t < 5) {
            ws[PART_OFF + blockIdx.x * 5 + t] =
                red[0][t] + red[1][t] + red[2][t] + red[3][t];
        }
    }

    // --- normalize visual rows (wave per node); int8 mode: quantize per-row ---
    char*  nvis8 = (char*)ws + NV_BYTE_OFF;
    float* inv   = ws + INV_OFF;   // int8 mode: qs[node]; fp32 fallback: 1/norm
    int wave  = gid >> 6;
    int nwave = stride >> 6;
    for (int node = wave; node < N_NODES; node += nwave) {
        const float4* row = (const float4*)(visual + (size_t)node * VD);
        float4 a = row[lane];
        float4 b = row[lane + 64];
        float p = a.x*a.x + a.y*a.y + a.z*a.z + a.w*a.w
                + b.x*b.x + b.y*b.y + b.z*b.z + b.w*b.w;
        float am = fmaxf(fmaxf(fmaxf(fabsf(a.x), fabsf(a.y)), fmaxf(fabsf(a.z), fabsf(a.w))),
                         fmaxf(fmaxf(fabsf(b.x), fabsf(b.y)), fmaxf(fabsf(b.z), fabsf(b.w))));
        for (int o = 32; o; o >>= 1) {
            p  += __shfl_xor(p, o, 64);
            am  = fmaxf(am, __shfl_xor(am, o, 64));
        }
        float r = 1.0f / fmaxf(sqrtf(p), 1e-8f);
        if (i8mode) {
            float vnmax = am * r;                       // max |element| of normalized row
            float qsc   = 127.0f / fmaxf(vnmax, 1e-20f);
            float rs    = r * qsc;                      // raw -> int8 code scale
            uint2 q;
            q.x = pack4i8(a.x, a.y, a.z, a.w, rs);
            q.y = pack4i8(b.x, b.y, b.z, b.w, rs);
            // lane-local 8 elems stored contiguously; identical layout on src
            // and dst rows, so the dot product is order-invariant.
            uint2* orow = (uint2*)(nvis8 + (size_t)node * 512);
            orow[lane] = q;
            if (lane == 0) inv[node] = vnmax * (1.0f / 127.0f);   // qs
        } else if (lane == 0) {
            inv[node] = r;
        }
    }
}

// ================= K2: fold partials + BN scalars + sarr (pre-scaled by qs) + deg hist ====
__global__ void __launch_bounds__(256) k2_sarr(
        const float* __restrict__ x,
        const int* __restrict__ ei,
        const float* __restrict__ w1, const float* __restrict__ b1,
        const float* __restrict__ gamma, const float* __restrict__ beta,
        const float* __restrict__ prelu_a,
        const float* __restrict__ w2, const float* __restrict__ b2,
        const float* __restrict__ wc, const float* __restrict__ wp,
        const float* __restrict__ ws_ro,
        float* __restrict__ sarr,
        float* __restrict__ deg, int i8mode) {
    __shared__ float red[4][5];
    __shared__ float s_S[5];
    __shared__ float s_scale[HID], s_shift[HID], s_u[HID], s_w1a[HID], s_w1b[HID];
    __shared__ float s_wpc[HID];
    __shared__ float s_sb;
    const float* part = ws_ro + PART_OFF;
    const float* qs   = ws_ro + INV_OFF;
    const int t    = threadIdx.x;
    const int lane = t & 63;

    {
        float S[5] = {0.f, 0.f, 0.f, 0.f, 0.f};
        for (int j = t; j < K1_BLOCKS; j += 256) {
            #pragma unroll
            for (int c = 0; c < 5; ++c) S[c] += part[j * 5 + c];
        }
        #pragma unroll
        for (int c = 0; c < 5; ++c)
            for (int o = 32; o; o >>= 1) S[c] += __shfl_xor(S[c], o, 64);
        int wv = t >> 6;
        if (lane == 0) {
            #pragma unroll
            for (int c = 0; c < 5; ++c) red[wv][c] = S[c];
        }
        __syncthreads();
        if (t < 5) s_S[t] = red[0][t] + red[1][t] + red[2][t] + red[3][t];
        __syncthreads();
    }

    if (t < HID) {
        float wpck = 0.f;
        for (int j = 0; j < HID; ++j) wpck += wp[j] * wc[j * HID + t];
        s_wpc[t] = wpck;
        const float invN = 1.0f / (float)N_NODES;
        float m0  = s_S[0] * invN, m1 = s_S[1] * invN;
        float v0  = fmaxf(s_S[2] * invN - m0 * m0, 0.f);
        float v1  = fmaxf(s_S[3] * invN - m1 * m1, 0.f);
        float c01 = s_S[4] * invN - m0 * m1;
        float a0 = w1[2 * t], a1 = w1[2 * t + 1];
        float mean = a0 * m0 + a1 * m1 + b1[t];
        float var  = fmaxf(a0 * a0 * v0 + a1 * a1 * v1 + 2.f * a0 * a1 * c01, 0.f);
        float rs    = 1.0f / sqrtf(var + 1e-5f);
        float scale = gamma[t] * rs;
        s_scale[t] = scale;
        s_shift[t] = beta[t] - mean * scale;
        s_w1a[t] = a0; s_w1b[t] = a1;
    }
    __syncthreads();
    if (t < HID) {
        float uu = 0.f;
        for (int k = 0; k < HID; ++k) uu += s_wpc[k] * w2[k * HID + t];
        s_u[t] = uu;
    }
    if (t == 0) {
        float sb = 0.f;
        for (int k = 0; k < HID; ++k) sb += s_wpc[k] * b2[k];
        s_sb = sb;
    }
    __syncthreads();
    const float aslope = prelu_a[0];
    const float sb = s_sb;
    for (int i = blockIdx.x * blockDim.x + t; i < N_NODES; i += gridDim.x * blockDim.x) {
        float2 xv = ((const float2*)x)[i];
        float sacc = sb;
        #pragma unroll
        for (int c = 0; c < HID; ++c) {
            float h  = s_w1a[c] * xv.x + s_w1b[c] * xv.y + b1[c];
            float tt = h * s_scale[c] + s_shift[c];
            tt = tt >= 0.f ? tt : aslope * tt;
            sacc += tt * s_u[c];
        }
        sarr[i] = i8mode ? sacc * qs[i] : sacc;   // fold src-side quant scale in
    }

    // --- deg histogram (independent of edge weights) ---
    for (int e = blockIdx.x * blockDim.x + t; e < E_EDGES; e += gridDim.x * blockDim.x) {
        atomicAdd(&deg[ei[E_EDGES + e]], 1.0f);
    }
}

// ===== K3: src-bucketed skip-scan edge kernel, 8-lane group per edge (int8 rows) =====
// 8 edges per wave-iteration in disjoint 8-lane groups:
//   - v_dot4_i32_i8 packed dot (4 elems / instr)
//   - 3-level butterfly reduces all 8 edges simultaneously
//   - 512 B rows: half the L2-miss bytes + lines of the fp16 version
__global__ void __launch_bounds__(256) k3_edge8(const int* __restrict__ ei,
                                                const float* __restrict__ ws_ro,
                                                float* __restrict__ acc,
                                                const float* __restrict__ sq) {
    const char* nvb = (const char*)ws_ro + NV_BYTE_OFF;
    const int lane = threadIdx.x & 63;
    const int sub  = lane & 7;                             // lane within 8-group
    const int g    = lane >> 3;                            // edge-group 0..7
    const int r    = blockIdx.x & 7;                       // src-bucket residue -> XCD
    const int q    = (blockIdx.x >> 3) * (blockDim.x >> 6) + (threadIdx.x >> 6);
    const int nq   = (gridDim.x >> 3) * (blockDim.x >> 6);
    const int nchunk = E_EDGES >> 6;                       // 7500 (exact)

    for (int c = q; c < nchunk; c += nq) {
        int idx = (c << 6) + lane;
        int s = ei[idx];
        int d = ei[E_EDGES + idx];
        bool mine = (s / BUCKET == r);
        float mys = mine ? sq[s] : 0.f;                    // qs[s]*sarr[s]
        unsigned long long m = __ballot(mine);
        while (m) {
            // extract up to 8 set bits; inactive slots duplicate slot 0
            int j0 = __ffsll(m) - 1;  m &= m - 1;
            int cnt = 1;
            int j1 = j0, j2 = j0, j3 = j0, j4 = j0, j5 = j0, j6 = j0, j7 = j0;
            if (m) { j1 = __ffsll(m) - 1; m &= m - 1; cnt = 2; }
            if (m) { j2 = __ffsll(m) - 1; m &= m - 1; cnt = 3; }
            if (m) { j3 = __ffsll(m) - 1; m &= m - 1; cnt = 4; }
            if (m) { j4 = __ffsll(m) - 1; m &= m - 1; cnt = 5; }
            if (m) { j5 = __ffsll(m) - 1; m &= m - 1; cnt = 6; }
            if (m) { j6 = __ffsll(m) - 1; m &= m - 1; cnt = 7; }
            if (m) { j7 = __ffsll(m) - 1; m &= m - 1; cnt = 8; }

            // group g pulls edge j_g (static ternary tree, no scratch array)
            int jsel = (g < 4) ? ((g < 2) ? (g == 0 ? j0 : j1) : (g == 2 ? j2 : j3))
                               : ((g < 6) ? (g == 4 ? j4 : j5) : (g == 6 ? j6 : j7));
            int   se = __shfl(s,   jsel, 64);
            int   de = __shfl(d,   jsel, 64);
            float sv = __shfl(mys, jsel, 64);

            // 8-lane group reads its edge's two 512B rows; per load instr a
            // group covers 128 contiguous bytes
            const uint4* sa = (const uint4*)(nvb + ((size_t)se << 9)) + sub;
            const uint4* da = (const uint4*)(nvb + ((size_t)de << 9)) + sub;
            uint4 A0 = sa[0];
            uint4 B0 = da[0];
            uint4 A1 = sa[8];
            uint4 B1 = da[8];
            uint4 A2 = sa[16];
            uint4 B2 = da[16];
            uint4 A3 = sa[24];
            uint4 B3 = da[24];

            int p = 0;
            p = edot4(A0.x, B0.x, p);
            p = edot4(A0.y, B0.y, p);
            p = edot4(A0.z, B0.z, p);
            p = edot4(A0.w, B0.w, p);
            p = edot4(A1.x, B1.x, p);
            p = edot4(A1.y, B1.y, p);
            p = edot4(A1.z, B1.z, p);
            p = edot4(A1.w, B1.w, p);
            p = edot4(A2.x, B2.x, p);
            p = edot4(A2.y, B2.y, p);
            p = edot4(A2.z, B2.z, p);
            p = edot4(A2.w, B2.w, p);
            p = edot4(A3.x, B3.x, p);
            p = edot4(A3.y, B3.y, p);
            p = edot4(A3.z, B3.z, p);
            p = edot4(A3.w, B3.w, p);

            // 3-level butterfly inside each 8-lane group: reduces all 8
            // edges simultaneously (offsets 4,2,1 never cross a group)
            p += __shfl_xor(p, 4, 64);
            p += __shfl_xor(p, 2, 64);
            p += __shfl_xor(p, 1, 64);

            if (sub == 0 && g < cnt) {
                atomicAdd(&acc[de], (float)p * sv);        // qs[d] applied in K4
            }
        }
    }
}

// fp32 fallback edge kernel (correctness path; deg handled in K2)
__global__ void __launch_bounds__(256) k3_edge32(const int* __restrict__ ei,
                                                 const float* __restrict__ visual,
                                                 const float* __restrict__ inv,
                                                 const float* __restrict__ sarr,
                                                 float* __restrict__ acc) {
    int wave  = (blockIdx.x * blockDim.x + threadIdx.x) >> 6;
    int lane  = threadIdx.x & 63;
    int nwave = (gridDim.x * blockDim.x) >> 6;
    for (int e = wave; e < E_EDGES; e += nwave) {
        int s = ei[e];
        int d = ei[E_EDGES + e];
        const float4* ra = (const float4*)(visual + (size_t)s * VD);
        const float4* rb = (const float4*)(visual + (size_t)d * VD);
        float4 a0 = ra[lane];
        float4 b0 = rb[lane];
        float4 a1 = ra[lane + 64];
        float4 b1 = rb[lane + 64];
        float p = a0.x*b0.x + a0.y*b0.y + a0.z*b0.z + a0.w*b0.w
                + a1.x*b1.x + a1.y*b1.y + a1.z*b1.z + a1.w*b1.w;
        for (int o = 32; o; o >>= 1) p += __shfl_xor(p, o, 64);
        if (lane == 0) {
            float w = p * inv[s] * inv[d];
            atomicAdd(&acc[d], w * sarr[s]);
        }
    }
}

// ================= K4: final (applies dst-side quant scale) =================
__global__ void k4_final(const float* __restrict__ acc, const float* __restrict__ deg,
                         const float* __restrict__ qs,
                         const float* __restrict__ bc, const float* __restrict__ wp,
                         const float* __restrict__ bp, float* __restrict__ out,
                         int n, int i8mode) {
    float K = bp[0];
    #pragma unroll
    for (int j = 0; j < HID; ++j) K += wp[j] * bc[j];
    for (int i = blockIdx.x * blockDim.x + threadIdx.x; i < n; i += gridDim.x * blockDim.x) {
        float a = acc[i];
        if (i8mode) a *= qs[i];
        out[i] = a / fmaxf(deg[i], 1.0f) + K;
    }
}

extern "C" void kernel_launch(void* const* d_in, const int* in_sizes, int n_in,
                              void* d_out, int out_size, void* d_ws, size_t ws_size,
                              hipStream_t stream) {
    const float* x       = (const float*)d_in[0];
    const float* visual  = (const float*)d_in[1];
    const int*   ei      = (const int*)  d_in[2];
    const float* w1      = (const float*)d_in[3];
    const float* b1      = (const float*)d_in[4];
    const float* gamma   = (const float*)d_in[5];
    const float* beta    = (const float*)d_in[6];
    const float* prelu_a = (const float*)d_in[7];
    const float* w2      = (const float*)d_in[8];
    const float* b2      = (const float*)d_in[9];
    const float* wc      = (const float*)d_in[10];
    const float* bc      = (const float*)d_in[11];
    const float* wp      = (const float*)d_in[12];
    const float* bp      = (const float*)d_in[13];
    float* out = (float*)d_out;

    float* ws   = (float*)d_ws;
    float* acc  = ws + ACC_OFF;
    float* deg  = ws + DEG_OFF;
    float* sarr = ws + SARR_OFF;
    float* inv  = ws + INV_OFF;   // qs in int8 mode

    bool i8ok = ws_size >= (size_t)NV_BYTE_OFF + (size_t)N_NODES * 512;

    k1_prep<<<K1_BLOCKS, 256, 0, stream>>>(x, visual, ws, i8ok ? 1 : 0);
    k2_sarr<<<512, 256, 0, stream>>>(x, ei, w1, b1, gamma, beta, prelu_a, w2, b2, wc, wp,
                                     ws, sarr, deg, i8ok ? 1 : 0);
    if (i8ok) {
        k3_edge8<<<4096, 256, 0, stream>>>(ei, ws, acc, sarr);
    } else {
        k3_edge32<<<4096, 256, 0, stream>>>(ei, visual, inv, sarr, acc);
    }
    k4_final<<<120, 256, 0, stream>>>(acc, deg, inv, bc, wp, bp, out, N_NODES, i8ok ? 1 : 0);
}

// Round 4
// 184.957 us; speedup vs baseline: 1.3874x; 1.0793x over previous
//
#include <hip/hip_runtime.h>
#include <hip/hip_fp16.h>
#include <math.h>

#define N_NODES 30000
#define E_EDGES 480000
#define VD      512
#define HID     32
#define BUCKET  3750   // rows per src-bucket; int8 rows: 3750 * 512B = 1.92 MB << 4 MB L2
#define K1_BLOCKS 512

// ws layout — BYTE-INTERVAL AUDIT (4-byte floats unless noted):
//   acc   floats [0, 30000)        = bytes [0, 120000)
//   deg   floats [30000, 60000)    = bytes [120000, 240000)
//   sarr  floats [60000, 90000)    = bytes [240000, 360000)   (holds qs[s]*sarr[s] in int8 mode)
//   part  floats [90000, 92560)    = bytes [360000, 370240)   (K1_BLOCKS x 5)
//   inv   floats [92560, 122560)   = bytes [370240, 490240)   (int8 mode: per-row qs; fp32 fallback: 1/norm)
//   nvis8 bytes  [524288, 15884288)                           (int8 rows, 512 B/row)
//   -> no overlaps; total need 15.9 MB
#define ACC_OFF  0
#define DEG_OFF  30000
#define SARR_OFF 60000
#define PART_OFF 90000
#define INV_OFF  92560
#define NV_BYTE_OFF 524288u

// packed int8 dot with i32 accumulate: v_dot4_i32_i8
__device__ inline int edot4(unsigned int a, unsigned int b, int c) {
#if __has_builtin(__builtin_amdgcn_sdot4)
    return __builtin_amdgcn_sdot4((int)a, (int)b, (int)c, false);
#else
    int r = c;
    r += (int)(signed char)(a)       * (int)(signed char)(b);
    r += (int)(signed char)(a >> 8)  * (int)(signed char)(b >> 8);
    r += (int)(signed char)(a >> 16) * (int)(signed char)(b >> 16);
    r += (int)(signed char)(a >> 24) * (int)(signed char)(b >> 24);
    return r;
#endif
}

__device__ inline unsigned int pack4i8(float x0, float x1, float x2, float x3, float sc) {
    int q0 = (int)rintf(x0 * sc);
    int q1 = (int)rintf(x1 * sc);
    int q2 = (int)rintf(x2 * sc);
    int q3 = (int)rintf(x3 * sc);
    return (unsigned int)(q0 & 255) | ((unsigned int)(q1 & 255) << 8) |
           ((unsigned int)(q2 & 255) << 16) | ((unsigned int)(q3 & 255) << 24);
}

// ================= K1: zero acc/deg + moment partials + normalize+quantize =====
// normalize phase: 16-lane group per row, 4 rows per wave (4-level butterfly
// amortized over 4 rows; N_NODES % 4 == 0 so no tail guard needed)
__global__ void __launch_bounds__(256) k1_prep(
        const float* __restrict__ x,
        const float* __restrict__ visual,
        float* __restrict__ ws, int i8mode) {
    const int t      = threadIdx.x;
    const int gid    = blockIdx.x * blockDim.x + t;
    const int stride = gridDim.x * blockDim.x;
    const int lane   = t & 63;

    // --- zero acc + deg ---
    for (int i = gid; i < 2 * N_NODES; i += stride) ws[i] = 0.f;

    // --- per-block moment partials of x ---
    {
        __shared__ float red[4][5];
        float s0 = 0.f, s1 = 0.f, s00 = 0.f, s11 = 0.f, s01 = 0.f;
        for (int i = gid; i < N_NODES; i += stride) {
            float2 v = ((const float2*)x)[i];
            s0  += v.x;       s1  += v.y;
            s00 += v.x * v.x; s11 += v.y * v.y;
            s01 += v.x * v.y;
        }
        for (int o = 32; o; o >>= 1) {
            s0  += __shfl_xor(s0,  o, 64);
            s1  += __shfl_xor(s1,  o, 64);
            s00 += __shfl_xor(s00, o, 64);
            s11 += __shfl_xor(s11, o, 64);
            s01 += __shfl_xor(s01, o, 64);
        }
        int wv = t >> 6;
        if (lane == 0) {
            red[wv][0] = s0; red[wv][1] = s1; red[wv][2] = s00;
            red[wv][3] = s11; red[wv][4] = s01;
        }
        __syncthreads();
        if (t < 5) {
            ws[PART_OFF + blockIdx.x * 5 + t] =
                red[0][t] + red[1][t] + red[2][t] + red[3][t];
        }
    }

    // --- normalize visual rows; int8 mode: quantize per-row ---
    char*  nvis8 = (char*)ws + NV_BYTE_OFF;
    float* inv   = ws + INV_OFF;   // int8 mode: qs[node]; fp32 fallback: 1/norm
    const int grp  = (lane >> 4);       // 16-lane group 0..3
    const int sub  = lane & 15;         // lane within group
    const int wave  = gid >> 6;
    const int nwave = stride >> 6;
    for (int base = wave * 4; base < N_NODES; base += nwave * 4) {
        const int node = base + grp;    // always < N_NODES (N % 4 == 0)
        const float4* row = (const float4*)(visual + (size_t)node * VD);
        float4 v0 = row[sub];
        float4 v1 = row[sub + 16];
        float4 v2 = row[sub + 32];
        float4 v3 = row[sub + 48];
        float4 v4 = row[sub + 64];
        float4 v5 = row[sub + 80];
        float4 v6 = row[sub + 96];
        float4 v7 = row[sub + 112];
        float p = 0.f, am = 0.f;
        #define ACCUM(vv) \
            p += vv.x*vv.x + vv.y*vv.y + vv.z*vv.z + vv.w*vv.w; \
            am = fmaxf(am, fmaxf(fmaxf(fabsf(vv.x), fabsf(vv.y)), \
                                 fmaxf(fabsf(vv.z), fabsf(vv.w))));
        ACCUM(v0) ACCUM(v1) ACCUM(v2) ACCUM(v3)
        ACCUM(v4) ACCUM(v5) ACCUM(v6) ACCUM(v7)
        #undef ACCUM
        // 4-level butterfly: offsets 8,4,2,1 stay inside the 16-lane group
        for (int o = 8; o; o >>= 1) {
            p  += __shfl_xor(p, o, 64);
            am  = fmaxf(am, __shfl_xor(am, o, 64));
        }
        float r = 1.0f / fmaxf(sqrtf(p), 1e-8f);
        if (i8mode) {
            float vnmax = am * r;                       // max |element| of normalized row
            float qsc   = 127.0f / fmaxf(vnmax, 1e-20f);
            float rs    = r * qsc;                      // raw -> int8 code scale
            unsigned int* orow = (unsigned int*)(nvis8 + (size_t)node * 512);
            orow[sub]       = pack4i8(v0.x, v0.y, v0.z, v0.w, rs);
            orow[sub + 16]  = pack4i8(v1.x, v1.y, v1.z, v1.w, rs);
            orow[sub + 32]  = pack4i8(v2.x, v2.y, v2.z, v2.w, rs);
            orow[sub + 48]  = pack4i8(v3.x, v3.y, v3.z, v3.w, rs);
            orow[sub + 64]  = pack4i8(v4.x, v4.y, v4.z, v4.w, rs);
            orow[sub + 80]  = pack4i8(v5.x, v5.y, v5.z, v5.w, rs);
            orow[sub + 96]  = pack4i8(v6.x, v6.y, v6.z, v6.w, rs);
            orow[sub + 112] = pack4i8(v7.x, v7.y, v7.z, v7.w, rs);
            if (sub == 0) inv[node] = vnmax * (1.0f / 127.0f);   // qs
        } else if (sub == 0) {
            inv[node] = r;
        }
    }
}

// ================= K2: fold partials + BN scalars + sarr (pre-scaled by qs) ====
__global__ void __launch_bounds__(256) k2_sarr(
        const float* __restrict__ x,
        const float* __restrict__ w1, const float* __restrict__ b1,
        const float* __restrict__ gamma, const float* __restrict__ beta,
        const float* __restrict__ prelu_a,
        const float* __restrict__ w2, const float* __restrict__ b2,
        const float* __restrict__ wc, const float* __restrict__ wp,
        const float* __restrict__ ws_ro,
        float* __restrict__ sarr, int i8mode) {
    __shared__ float red[4][5];
    __shared__ float s_S[5];
    __shared__ float s_scale[HID], s_shift[HID], s_u[HID], s_w1a[HID], s_w1b[HID];
    __shared__ float s_wpc[HID];
    __shared__ float s_sb;
    const float* part = ws_ro + PART_OFF;
    const float* qs   = ws_ro + INV_OFF;
    const int t    = threadIdx.x;
    const int lane = t & 63;

    {
        float S[5] = {0.f, 0.f, 0.f, 0.f, 0.f};
        for (int j = t; j < K1_BLOCKS; j += 256) {
            #pragma unroll
            for (int c = 0; c < 5; ++c) S[c] += part[j * 5 + c];
        }
        #pragma unroll
        for (int c = 0; c < 5; ++c)
            for (int o = 32; o; o >>= 1) S[c] += __shfl_xor(S[c], o, 64);
        int wv = t >> 6;
        if (lane == 0) {
            #pragma unroll
            for (int c = 0; c < 5; ++c) red[wv][c] = S[c];
        }
        __syncthreads();
        if (t < 5) s_S[t] = red[0][t] + red[1][t] + red[2][t] + red[3][t];
        __syncthreads();
    }

    if (t < HID) {
        float wpck = 0.f;
        for (int j = 0; j < HID; ++j) wpck += wp[j] * wc[j * HID + t];
        s_wpc[t] = wpck;
        const float invN = 1.0f / (float)N_NODES;
        float m0  = s_S[0] * invN, m1 = s_S[1] * invN;
        float v0  = fmaxf(s_S[2] * invN - m0 * m0, 0.f);
        float v1  = fmaxf(s_S[3] * invN - m1 * m1, 0.f);
        float c01 = s_S[4] * invN - m0 * m1;
        float a0 = w1[2 * t], a1 = w1[2 * t + 1];
        float mean = a0 * m0 + a1 * m1 + b1[t];
        float var  = fmaxf(a0 * a0 * v0 + a1 * a1 * v1 + 2.f * a0 * a1 * c01, 0.f);
        float rs    = 1.0f / sqrtf(var + 1e-5f);
        float scale = gamma[t] * rs;
        s_scale[t] = scale;
        s_shift[t] = beta[t] - mean * scale;
        s_w1a[t] = a0; s_w1b[t] = a1;
    }
    __syncthreads();
    if (t < HID) {
        float uu = 0.f;
        for (int k = 0; k < HID; ++k) uu += s_wpc[k] * w2[k * HID + t];
        s_u[t] = uu;
    }
    if (t == 0) {
        float sb = 0.f;
        for (int k = 0; k < HID; ++k) sb += s_wpc[k] * b2[k];
        s_sb = sb;
    }
    __syncthreads();
    const float aslope = prelu_a[0];
    const float sb = s_sb;
    for (int i = blockIdx.x * blockDim.x + t; i < N_NODES; i += gridDim.x * blockDim.x) {
        float2 xv = ((const float2*)x)[i];
        float sacc = sb;
        #pragma unroll
        for (int c = 0; c < HID; ++c) {
            float h  = s_w1a[c] * xv.x + s_w1b[c] * xv.y + b1[c];
            float tt = h * s_scale[c] + s_shift[c];
            tt = tt >= 0.f ? tt : aslope * tt;
            sacc += tt * s_u[c];
        }
        sarr[i] = i8mode ? sacc * qs[i] : sacc;   // fold src-side quant scale in
    }
}

// ===== K3: src-bucketed skip-scan edge kernel, 8-lane group per edge (int8 rows) =====
// 8 edges per wave-iteration in disjoint 8-lane groups; deg atomics live here
// (hidden under fetch latency — moving them to K2 cost +17-22 us e2e, R1 evidence)
__global__ void __launch_bounds__(256) k3_edge8(const int* __restrict__ ei,
                                                const float* __restrict__ ws_ro,
                                                float* __restrict__ acc,
                                                float* __restrict__ deg,
                                                const float* __restrict__ sq) {
    const char* nvb = (const char*)ws_ro + NV_BYTE_OFF;
    const int lane = threadIdx.x & 63;
    const int sub  = lane & 7;                             // lane within 8-group
    const int g    = lane >> 3;                            // edge-group 0..7
    const int r    = blockIdx.x & 7;                       // src-bucket residue -> XCD
    const int q    = (blockIdx.x >> 3) * (blockDim.x >> 6) + (threadIdx.x >> 6);
    const int nq   = (gridDim.x >> 3) * (blockDim.x >> 6);
    const int nchunk = E_EDGES >> 6;                       // 7500 (exact)

    for (int c = q; c < nchunk; c += nq) {
        int idx = (c << 6) + lane;
        int s = ei[idx];
        int d = ei[E_EDGES + idx];
        bool mine = (s / BUCKET == r);
        float mys = mine ? sq[s] : 0.f;                    // qs[s]*sarr[s]
        unsigned long long m = __ballot(mine);
        while (m) {
            // extract up to 8 set bits; inactive slots duplicate slot 0
            int j0 = __ffsll(m) - 1;  m &= m - 1;
            int cnt = 1;
            int j1 = j0, j2 = j0, j3 = j0, j4 = j0, j5 = j0, j6 = j0, j7 = j0;
            if (m) { j1 = __ffsll(m) - 1; m &= m - 1; cnt = 2; }
            if (m) { j2 = __ffsll(m) - 1; m &= m - 1; cnt = 3; }
            if (m) { j3 = __ffsll(m) - 1; m &= m - 1; cnt = 4; }
            if (m) { j4 = __ffsll(m) - 1; m &= m - 1; cnt = 5; }
            if (m) { j5 = __ffsll(m) - 1; m &= m - 1; cnt = 6; }
            if (m) { j6 = __ffsll(m) - 1; m &= m - 1; cnt = 7; }
            if (m) { j7 = __ffsll(m) - 1; m &= m - 1; cnt = 8; }

            // group g pulls edge j_g (static ternary tree, no scratch array)
            int jsel = (g < 4) ? ((g < 2) ? (g == 0 ? j0 : j1) : (g == 2 ? j2 : j3))
                               : ((g < 6) ? (g == 4 ? j4 : j5) : (g == 6 ? j6 : j7));
            int   se = __shfl(s,   jsel, 64);
            int   de = __shfl(d,   jsel, 64);
            float sv = __shfl(mys, jsel, 64);

            // 8-lane group reads its edge's two 512B rows; per load instr a
            // group covers 128 contiguous bytes
            const uint4* sa = (const uint4*)(nvb + ((size_t)se << 9)) + sub;
            const uint4* da = (const uint4*)(nvb + ((size_t)de << 9)) + sub;
            uint4 A0 = sa[0];
            uint4 B0 = da[0];
            uint4 A1 = sa[8];
            uint4 B1 = da[8];
            uint4 A2 = sa[16];
            uint4 B2 = da[16];
            uint4 A3 = sa[24];
            uint4 B3 = da[24];

            int p = 0;
            p = edot4(A0.x, B0.x, p);
            p = edot4(A0.y, B0.y, p);
            p = edot4(A0.z, B0.z, p);
            p = edot4(A0.w, B0.w, p);
            p = edot4(A1.x, B1.x, p);
            p = edot4(A1.y, B1.y, p);
            p = edot4(A1.z, B1.z, p);
            p = edot4(A1.w, B1.w, p);
            p = edot4(A2.x, B2.x, p);
            p = edot4(A2.y, B2.y, p);
            p = edot4(A2.z, B2.z, p);
            p = edot4(A2.w, B2.w, p);
            p = edot4(A3.x, B3.x, p);
            p = edot4(A3.y, B3.y, p);
            p = edot4(A3.z, B3.z, p);
            p = edot4(A3.w, B3.w, p);

            // 3-level butterfly inside each 8-lane group: reduces all 8
            // edges simultaneously (offsets 4,2,1 never cross a group)
            p += __shfl_xor(p, 4, 64);
            p += __shfl_xor(p, 2, 64);
            p += __shfl_xor(p, 1, 64);

            if (sub == 0 && g < cnt) {
                atomicAdd(&acc[de], (float)p * sv);        // qs[d] applied in K4
                atomicAdd(&deg[de], 1.0f);
            }
        }
    }
}

// fp32 fallback edge kernel (correctness path)
__global__ void __launch_bounds__(256) k3_edge32(const int* __restrict__ ei,
                                                 const float* __restrict__ visual,
                                                 const float* __restrict__ inv,
                                                 const float* __restrict__ sarr,
                                                 float* __restrict__ acc,
                                                 float* __restrict__ deg) {
    int wave  = (blockIdx.x * blockDim.x + threadIdx.x) >> 6;
    int lane  = threadIdx.x & 63;
    int nwave = (gridDim.x * blockDim.x) >> 6;
    for (int e = wave; e < E_EDGES; e += nwave) {
        int s = ei[e];
        int d = ei[E_EDGES + e];
        const float4* ra = (const float4*)(visual + (size_t)s * VD);
        const float4* rb = (const float4*)(visual + (size_t)d * VD);
        float4 a0 = ra[lane];
        float4 b0 = rb[lane];
        float4 a1 = ra[lane + 64];
        float4 b1 = rb[lane + 64];
        float p = a0.x*b0.x + a0.y*b0.y + a0.z*b0.z + a0.w*b0.w
                + a1.x*b1.x + a1.y*b1.y + a1.z*b1.z + a1.w*b1.w;
        for (int o = 32; o; o >>= 1) p += __shfl_xor(p, o, 64);
        if (lane == 0) {
            float w = p * inv[s] * inv[d];
            atomicAdd(&acc[d], w * sarr[s]);
            atomicAdd(&deg[d], 1.0f);
        }
    }
}

// ================= K4: final (applies dst-side quant scale) =================
__global__ void k4_final(const float* __restrict__ acc, const float* __restrict__ deg,
                         const float* __restrict__ qs,
                         const float* __restrict__ bc, const float* __restrict__ wp,
                         const float* __restrict__ bp, float* __restrict__ out,
                         int n, int i8mode) {
    float K = bp[0];
    #pragma unroll
    for (int j = 0; j < HID; ++j) K += wp[j] * bc[j];
    for (int i = blockIdx.x * blockDim.x + threadIdx.x; i < n; i += gridDim.x * blockDim.x) {
        float a = acc[i];
        if (i8mode) a *= qs[i];
        out[i] = a / fmaxf(deg[i], 1.0f) + K;
    }
}

extern "C" void kernel_launch(void* const* d_in, const int* in_sizes, int n_in,
                              void* d_out, int out_size, void* d_ws, size_t ws_size,
                              hipStream_t stream) {
    const float* x       = (const float*)d_in[0];
    const float* visual  = (const float*)d_in[1];
    const int*   ei      = (const int*)  d_in[2];
    const float* w1      = (const float*)d_in[3];
    const float* b1      = (const float*)d_in[4];
    const float* gamma   = (const float*)d_in[5];
    const float* beta    = (const float*)d_in[6];
    const float* prelu_a = (const float*)d_in[7];
    const float* w2      = (const float*)d_in[8];
    const float* b2      = (const float*)d_in[9];
    const float* wc      = (const float*)d_in[10];
    const float* bc      = (const float*)d_in[11];
    const float* wp      = (const float*)d_in[12];
    const float* bp      = (const float*)d_in[13];
    float* out = (float*)d_out;

    float* ws   = (float*)d_ws;
    float* acc  = ws + ACC_OFF;
    float* deg  = ws + DEG_OFF;
    float* sarr = ws + SARR_OFF;
    float* inv  = ws + INV_OFF;   // qs in int8 mode

    bool i8ok = ws_size >= (size_t)NV_BYTE_OFF + (size_t)N_NODES * 512;

    k1_prep<<<K1_BLOCKS, 256, 0, stream>>>(x, visual, ws, i8ok ? 1 : 0);
    k2_sarr<<<512, 256, 0, stream>>>(x, w1, b1, gamma, beta, prelu_a, w2, b2, wc, wp,
                                     ws, sarr, i8ok ? 1 : 0);
    if (i8ok) {
        k3_edge8<<<4096, 256, 0, stream>>>(ei, ws, acc, deg, sarr);
    } else {
        k3_edge32<<<4096, 256, 0, stream>>>(ei, visual, inv, sarr, acc, deg);
    }
    k4_final<<<120, 256, 0, stream>>>(acc, deg, inv, bc, wp, bp, out, N_NODES, i8ok ? 1 : 0);
}

// Round 5
// 167.327 us; speedup vs baseline: 1.5336x; 1.1054x over previous
//
#include <hip/hip_runtime.h>
#include <hip/hip_fp16.h>
#include <math.h>

#define N_NODES 30000
#define E_EDGES 480000
#define VD      512
#define HID     32
#define BUCKET  3750   // rows per src-bucket; int8 rows: 3750 * 512B = 1.92 MB << 4 MB L2
#define K1_BLOCKS 512
#define BIG_ENC 1048576.0   // 2^20: deg-count encoding step inside the f64 accumulator

// ws layout — BYTE-INTERVAL AUDIT:
//   accD  doubles [0, 30000)        = bytes [0, 240000)      (packed acc + cnt*2^20)
//   sarr  floats  [60000, 90000)    = bytes [240000, 360000) (holds qs[s]*sarr[s] in int8 mode)
//   part  floats  [90000, 92560)    = bytes [360000, 370240) (K1_BLOCKS x 5)
//   inv   floats  [92560, 122560)   = bytes [370240, 490240) (int8: per-row qs; fp32 fallback: 1/norm)
//   nvis8 bytes   [524288, 15884288)                          (int8 rows, 512 B/row)
//   ei16  bytes   [15884288, 17804288)                        (packed ushort2 per edge)
//   -> no overlaps; total need 17.81 MB
#define SARR_OFF 60000
#define PART_OFF 90000
#define INV_OFF  92560
#define NV_BYTE_OFF   524288u
#define EI16_BYTE_OFF 15884288u

// guaranteed-native f64 atomic add (global_atomic_add_f64); plain atomicAdd
// may lower to a CAS loop depending on fp-atomics flags
__device__ inline void atomAddF64(double* p, double v) {
#if defined(__HIP_PLATFORM_AMD__)
    unsafeAtomicAdd(p, v);
#else
    atomicAdd(p, v);
#endif
}

// packed int8 dot with i32 accumulate: v_dot4_i32_i8
__device__ inline int edot4(unsigned int a, unsigned int b, int c) {
#if __has_builtin(__builtin_amdgcn_sdot4)
    return __builtin_amdgcn_sdot4((int)a, (int)b, (int)c, false);
#else
    int r = c;
    r += (int)(signed char)(a)       * (int)(signed char)(b);
    r += (int)(signed char)(a >> 8)  * (int)(signed char)(b >> 8);
    r += (int)(signed char)(a >> 16) * (int)(signed char)(b >> 16);
    r += (int)(signed char)(a >> 24) * (int)(signed char)(b >> 24);
    return r;
#endif
}

__device__ inline unsigned int pack4i8(float x0, float x1, float x2, float x3, float sc) {
    int q0 = (int)rintf(x0 * sc);
    int q1 = (int)rintf(x1 * sc);
    int q2 = (int)rintf(x2 * sc);
    int q3 = (int)rintf(x3 * sc);
    return (unsigned int)(q0 & 255) | ((unsigned int)(q1 & 255) << 8) |
           ((unsigned int)(q2 & 255) << 16) | ((unsigned int)(q3 & 255) << 24);
}

// ================= K1: zero accD + moment partials + ei16 pack + normalize+quantize =====
__global__ void __launch_bounds__(256) k1_prep(
        const float* __restrict__ x,
        const float* __restrict__ visual,
        const int* __restrict__ ei,
        float* __restrict__ ws, int i8mode) {
    const int t      = threadIdx.x;
    const int gid    = blockIdx.x * blockDim.x + t;
    const int stride = gridDim.x * blockDim.x;
    const int lane   = t & 63;

    // --- zero accD (30000 doubles = 60000 float-words) ---
    for (int i = gid; i < 2 * N_NODES; i += stride) ws[i] = 0.f;

    // --- pack edge indices: (src,dst) -> one uint (both < 30000 < 2^16) ---
    {
        unsigned int* ei16 = (unsigned int*)((char*)ws + EI16_BYTE_OFF);
        for (int e = gid; e < E_EDGES; e += stride) {
            unsigned int s = (unsigned int)ei[e];
            unsigned int d = (unsigned int)ei[E_EDGES + e];
            ei16[e] = s | (d << 16);
        }
    }

    // --- per-block moment partials of x ---
    {
        __shared__ float red[4][5];
        float s0 = 0.f, s1 = 0.f, s00 = 0.f, s11 = 0.f, s01 = 0.f;
        for (int i = gid; i < N_NODES; i += stride) {
            float2 v = ((const float2*)x)[i];
            s0  += v.x;       s1  += v.y;
            s00 += v.x * v.x; s11 += v.y * v.y;
            s01 += v.x * v.y;
        }
        for (int o = 32; o; o >>= 1) {
            s0  += __shfl_xor(s0,  o, 64);
            s1  += __shfl_xor(s1,  o, 64);
            s00 += __shfl_xor(s00, o, 64);
            s11 += __shfl_xor(s11, o, 64);
            s01 += __shfl_xor(s01, o, 64);
        }
        int wv = t >> 6;
        if (lane == 0) {
            red[wv][0] = s0; red[wv][1] = s1; red[wv][2] = s00;
            red[wv][3] = s11; red[wv][4] = s01;
        }
        __syncthreads();
        if (t < 5) {
            ws[PART_OFF + blockIdx.x * 5 + t] =
                red[0][t] + red[1][t] + red[2][t] + red[3][t];
        }
    }

    // --- normalize visual rows; int8 mode: quantize per-row ---
    // 16-lane group per row, 4 rows per wave (N_NODES % 4 == 0, no tail)
    char*  nvis8 = (char*)ws + NV_BYTE_OFF;
    float* inv   = ws + INV_OFF;   // int8 mode: qs[node]; fp32 fallback: 1/norm
    const int grp  = (lane >> 4);       // 16-lane group 0..3
    const int sub  = lane & 15;         // lane within group
    const int wave  = gid >> 6;
    const int nwave = stride >> 6;
    for (int base = wave * 4; base < N_NODES; base += nwave * 4) {
        const int node = base + grp;    // always < N_NODES (N % 4 == 0)
        const float4* row = (const float4*)(visual + (size_t)node * VD);
        float4 v0 = row[sub];
        float4 v1 = row[sub + 16];
        float4 v2 = row[sub + 32];
        float4 v3 = row[sub + 48];
        float4 v4 = row[sub + 64];
        float4 v5 = row[sub + 80];
        float4 v6 = row[sub + 96];
        float4 v7 = row[sub + 112];
        float p = 0.f, am = 0.f;
        #define ACCUM(vv) \
            p += vv.x*vv.x + vv.y*vv.y + vv.z*vv.z + vv.w*vv.w; \
            am = fmaxf(am, fmaxf(fmaxf(fabsf(vv.x), fabsf(vv.y)), \
                                 fmaxf(fabsf(vv.z), fabsf(vv.w))));
        ACCUM(v0) ACCUM(v1) ACCUM(v2) ACCUM(v3)
        ACCUM(v4) ACCUM(v5) ACCUM(v6) ACCUM(v7)
        #undef ACCUM
        // 4-level butterfly: offsets 8,4,2,1 stay inside the 16-lane group
        for (int o = 8; o; o >>= 1) {
            p  += __shfl_xor(p, o, 64);
            am  = fmaxf(am, __shfl_xor(am, o, 64));
        }
        float r = 1.0f / fmaxf(sqrtf(p), 1e-8f);
        if (i8mode) {
            float vnmax = am * r;                       // max |element| of normalized row
            float qsc   = 127.0f / fmaxf(vnmax, 1e-20f);
            float rs    = r * qsc;                      // raw -> int8 code scale
            unsigned int* orow = (unsigned int*)(nvis8 + (size_t)node * 512);
            orow[sub]       = pack4i8(v0.x, v0.y, v0.z, v0.w, rs);
            orow[sub + 16]  = pack4i8(v1.x, v1.y, v1.z, v1.w, rs);
            orow[sub + 32]  = pack4i8(v2.x, v2.y, v2.z, v2.w, rs);
            orow[sub + 48]  = pack4i8(v3.x, v3.y, v3.z, v3.w, rs);
            orow[sub + 64]  = pack4i8(v4.x, v4.y, v4.z, v4.w, rs);
            orow[sub + 80]  = pack4i8(v5.x, v5.y, v5.z, v5.w, rs);
            orow[sub + 96]  = pack4i8(v6.x, v6.y, v6.z, v6.w, rs);
            orow[sub + 112] = pack4i8(v7.x, v7.y, v7.z, v7.w, rs);
            if (sub == 0) inv[node] = vnmax * (1.0f / 127.0f);   // qs
        } else if (sub == 0) {
            inv[node] = r;
        }
    }
}

// ================= K2: fold partials + BN scalars + sarr (pre-scaled by qs) ====
__global__ void __launch_bounds__(256) k2_sarr(
        const float* __restrict__ x,
        const float* __restrict__ w1, const float* __restrict__ b1,
        const float* __restrict__ gamma, const float* __restrict__ beta,
        const float* __restrict__ prelu_a,
        const float* __restrict__ w2, const float* __restrict__ b2,
        const float* __restrict__ wc, const float* __restrict__ wp,
        const float* __restrict__ ws_ro,
        float* __restrict__ sarr, int i8mode) {
    __shared__ float red[4][5];
    __shared__ float s_S[5];
    __shared__ float s_scale[HID], s_shift[HID], s_u[HID], s_w1a[HID], s_w1b[HID];
    __shared__ float s_wpc[HID];
    __shared__ float s_sb;
    const float* part = ws_ro + PART_OFF;
    const float* qs   = ws_ro + INV_OFF;
    const int t    = threadIdx.x;
    const int lane = t & 63;

    {
        float S[5] = {0.f, 0.f, 0.f, 0.f, 0.f};
        for (int j = t; j < K1_BLOCKS; j += 256) {
            #pragma unroll
            for (int c = 0; c < 5; ++c) S[c] += part[j * 5 + c];
        }
        #pragma unroll
        for (int c = 0; c < 5; ++c)
            for (int o = 32; o; o >>= 1) S[c] += __shfl_xor(S[c], o, 64);
        int wv = t >> 6;
        if (lane == 0) {
            #pragma unroll
            for (int c = 0; c < 5; ++c) red[wv][c] = S[c];
        }
        __syncthreads();
        if (t < 5) s_S[t] = red[0][t] + red[1][t] + red[2][t] + red[3][t];
        __syncthreads();
    }

    if (t < HID) {
        float wpck = 0.f;
        for (int j = 0; j < HID; ++j) wpck += wp[j] * wc[j * HID + t];
        s_wpc[t] = wpck;
        const float invN = 1.0f / (float)N_NODES;
        float m0  = s_S[0] * invN, m1 = s_S[1] * invN;
        float v0  = fmaxf(s_S[2] * invN - m0 * m0, 0.f);
        float v1  = fmaxf(s_S[3] * invN - m1 * m1, 0.f);
        float c01 = s_S[4] * invN - m0 * m1;
        float a0 = w1[2 * t], a1 = w1[2 * t + 1];
        float mean = a0 * m0 + a1 * m1 + b1[t];
        float var  = fmaxf(a0 * a0 * v0 + a1 * a1 * v1 + 2.f * a0 * a1 * c01, 0.f);
        float rs    = 1.0f / sqrtf(var + 1e-5f);
        float scale = gamma[t] * rs;
        s_scale[t] = scale;
        s_shift[t] = beta[t] - mean * scale;
        s_w1a[t] = a0; s_w1b[t] = a1;
    }
    __syncthreads();
    if (t < HID) {
        float uu = 0.f;
        for (int k = 0; k < HID; ++k) uu += s_wpc[k] * w2[k * HID + t];
        s_u[t] = uu;
    }
    if (t == 0) {
        float sb = 0.f;
        for (int k = 0; k < HID; ++k) sb += s_wpc[k] * b2[k];
        s_sb = sb;
    }
    __syncthreads();
    const float aslope = prelu_a[0];
    const float sb = s_sb;
    for (int i = blockIdx.x * blockDim.x + t; i < N_NODES; i += gridDim.x * blockDim.x) {
        float2 xv = ((const float2*)x)[i];
        float sacc = sb;
        #pragma unroll
        for (int c = 0; c < HID; ++c) {
            float h  = s_w1a[c] * xv.x + s_w1b[c] * xv.y + b1[c];
            float tt = h * s_scale[c] + s_shift[c];
            tt = tt >= 0.f ? tt : aslope * tt;
            sacc += tt * s_u[c];
        }
        sarr[i] = i8mode ? sacc * qs[i] : sacc;   // fold src-side quant scale in
    }
}

// ===== K3: src-bucketed skip-scan edge kernel, 8-lane group per edge (int8 rows) =====
// 8 edges per wave-iteration in disjoint 8-lane groups. ONE f64 atomic per edge
// packs acc + deg (count * 2^20): atomics are memory-side 32B transactions on
// this chip (R4 evidence: WRITE_SIZE == 32B x atomic count), so halving the
// atomic count halves the atomic write traffic.
__global__ void __launch_bounds__(256) k3_edge8(const unsigned int* __restrict__ ei16,
                                                const float* __restrict__ ws_ro,
                                                double* __restrict__ accD,
                                                const float* __restrict__ sq) {
    const char* nvb = (const char*)ws_ro + NV_BYTE_OFF;
    const int lane = threadIdx.x & 63;
    const int sub  = lane & 7;                             // lane within 8-group
    const int g    = lane >> 3;                            // edge-group 0..7
    const int r    = blockIdx.x & 7;                       // src-bucket residue -> XCD
    const int q    = (blockIdx.x >> 3) * (blockDim.x >> 6) + (threadIdx.x >> 6);
    const int nq   = (gridDim.x >> 3) * (blockDim.x >> 6);
    const int nchunk = E_EDGES >> 6;                       // 7500 (exact)

    for (int c = q; c < nchunk; c += nq) {
        int idx = (c << 6) + lane;
        unsigned int sd = ei16[idx];
        int s = (int)(sd & 0xffffu);
        int d = (int)(sd >> 16);
        bool mine = (s / BUCKET == r);
        float mys = mine ? sq[s] : 0.f;                    // qs[s]*sarr[s]
        unsigned long long m = __ballot(mine);
        while (m) {
            // extract up to 8 set bits; inactive slots duplicate slot 0
            int j0 = __ffsll(m) - 1;  m &= m - 1;
            int cnt = 1;
            int j1 = j0, j2 = j0, j3 = j0, j4 = j0, j5 = j0, j6 = j0, j7 = j0;
            if (m) { j1 = __ffsll(m) - 1; m &= m - 1; cnt = 2; }
            if (m) { j2 = __ffsll(m) - 1; m &= m - 1; cnt = 3; }
            if (m) { j3 = __ffsll(m) - 1; m &= m - 1; cnt = 4; }
            if (m) { j4 = __ffsll(m) - 1; m &= m - 1; cnt = 5; }
            if (m) { j5 = __ffsll(m) - 1; m &= m - 1; cnt = 6; }
            if (m) { j6 = __ffsll(m) - 1; m &= m - 1; cnt = 7; }
            if (m) { j7 = __ffsll(m) - 1; m &= m - 1; cnt = 8; }

            // group g pulls edge j_g (static ternary tree, no scratch array)
            int jsel = (g < 4) ? ((g < 2) ? (g == 0 ? j0 : j1) : (g == 2 ? j2 : j3))
                               : ((g < 6) ? (g == 4 ? j4 : j5) : (g == 6 ? j6 : j7));
            int   se = __shfl(s,   jsel, 64);
            int   de = __shfl(d,   jsel, 64);
            float sv = __shfl(mys, jsel, 64);

            // 8-lane group reads its edge's two 512B rows; per load instr a
            // group covers 128 contiguous bytes
            const uint4* sa = (const uint4*)(nvb + ((size_t)se << 9)) + sub;
            const uint4* da = (const uint4*)(nvb + ((size_t)de << 9)) + sub;
            uint4 A0 = sa[0];
            uint4 B0 = da[0];
            uint4 A1 = sa[8];
            uint4 B1 = da[8];
            uint4 A2 = sa[16];
            uint4 B2 = da[16];
            uint4 A3 = sa[24];
            uint4 B3 = da[24];

            int p = 0;
            p = edot4(A0.x, B0.x, p);
            p = edot4(A0.y, B0.y, p);
            p = edot4(A0.z, B0.z, p);
            p = edot4(A0.w, B0.w, p);
            p = edot4(A1.x, B1.x, p);
            p = edot4(A1.y, B1.y, p);
            p = edot4(A1.z, B1.z, p);
            p = edot4(A1.w, B1.w, p);
            p = edot4(A2.x, B2.x, p);
            p = edot4(A2.y, B2.y, p);
            p = edot4(A2.z, B2.z, p);
            p = edot4(A2.w, B2.w, p);
            p = edot4(A3.x, B3.x, p);
            p = edot4(A3.y, B3.y, p);
            p = edot4(A3.z, B3.z, p);
            p = edot4(A3.w, B3.w, p);

            // 3-level butterfly inside each 8-lane group: reduces all 8
            // edges simultaneously (offsets 4,2,1 never cross a group)
            p += __shfl_xor(p, 4, 64);
            p += __shfl_xor(p, 2, 64);
            p += __shfl_xor(p, 1, 64);

            if (sub == 0 && g < cnt) {
                // packed: acc contribution + deg count (exact in f64 mantissa;
                // |sum acc| << 2^19 by magnitude analysis, so decode is exact)
                atomAddF64(&accD[de], (double)((float)p * sv) + BIG_ENC);
            }
        }
    }
}

// fp32 fallback edge kernel (correctness path; same packed-f64 accumulator)
__global__ void __launch_bounds__(256) k3_edge32(const int* __restrict__ ei,
                                                 const float* __restrict__ visual,
                                                 const float* __restrict__ inv,
                                                 const float* __restrict__ sarr,
                                                 double* __restrict__ accD) {
    int wave  = (blockIdx.x * blockDim.x + threadIdx.x) >> 6;
    int lane  = threadIdx.x & 63;
    int nwave = (gridDim.x * blockDim.x) >> 6;
    for (int e = wave; e < E_EDGES; e += nwave) {
        int s = ei[e];
        int d = ei[E_EDGES + e];
        const float4* ra = (const float4*)(visual + (size_t)s * VD);
        const float4* rb = (const float4*)(visual + (size_t)d * VD);
        float4 a0 = ra[lane];
        float4 b0 = rb[lane];
        float4 a1 = ra[lane + 64];
        float4 b1 = rb[lane + 64];
        float p = a0.x*b0.x + a0.y*b0.y + a0.z*b0.z + a0.w*b0.w
                + a1.x*b1.x + a1.y*b1.y + a1.z*b1.z + a1.w*b1.w;
        for (int o = 32; o; o >>= 1) p += __shfl_xor(p, o, 64);
        if (lane == 0) {
            float w = p * inv[s] * inv[d];
            atomAddF64(&accD[d], (double)(w * sarr[s]) + BIG_ENC);
        }
    }
}

// ================= K4: final (decode packed acc/deg; apply dst-side quant scale) ===
__global__ void k4_final(const double* __restrict__ accD,
                         const float* __restrict__ qs,
                         const float* __restrict__ bc, const float* __restrict__ wp,
                         const float* __restrict__ bp, float* __restrict__ out,
                         int n, int i8mode) {
    float K = bp[0];
    #pragma unroll
    for (int j = 0; j < HID; ++j) K += wp[j] * bc[j];
    for (int i = blockIdx.x * blockDim.x + threadIdx.x; i < n; i += gridDim.x * blockDim.x) {
        double total = accD[i];
        int cnt = (int)__double2ll_rn(total * (1.0 / BIG_ENC));
        float a = (float)(total - (double)cnt * BIG_ENC);
        if (i8mode) a *= qs[i];
        out[i] = a / (float)max(cnt, 1) + K;
    }
}

extern "C" void kernel_launch(void* const* d_in, const int* in_sizes, int n_in,
                              void* d_out, int out_size, void* d_ws, size_t ws_size,
                              hipStream_t stream) {
    const float* x       = (const float*)d_in[0];
    const float* visual  = (const float*)d_in[1];
    const int*   ei      = (const int*)  d_in[2];
    const float* w1      = (const float*)d_in[3];
    const float* b1      = (const float*)d_in[4];
    const float* gamma   = (const float*)d_in[5];
    const float* beta    = (const float*)d_in[6];
    const float* prelu_a = (const float*)d_in[7];
    const float* w2      = (const float*)d_in[8];
    const float* b2      = (const float*)d_in[9];
    const float* wc      = (const float*)d_in[10];
    const float* bc      = (const float*)d_in[11];
    const float* wp      = (const float*)d_in[12];
    const float* bp      = (const float*)d_in[13];
    float* out = (float*)d_out;

    float*  ws   = (float*)d_ws;
    double* accD = (double*)d_ws;
    float*  sarr = ws + SARR_OFF;
    float*  inv  = ws + INV_OFF;   // qs in int8 mode
    unsigned int* ei16 = (unsigned int*)((char*)d_ws + EI16_BYTE_OFF);

    bool i8ok = ws_size >= (size_t)EI16_BYTE_OFF + (size_t)E_EDGES * 4;

    k1_prep<<<K1_BLOCKS, 256, 0, stream>>>(x, visual, ei, ws, i8ok ? 1 : 0);
    k2_sarr<<<512, 256, 0, stream>>>(x, w1, b1, gamma, beta, prelu_a, w2, b2, wc, wp,
                                     ws, sarr, i8ok ? 1 : 0);
    if (i8ok) {
        k3_edge8<<<4096, 256, 0, stream>>>(ei16, ws, accD, sarr);
    } else {
        k3_edge32<<<4096, 256, 0, stream>>>(ei, visual, inv, sarr, accD);
    }
    k4_final<<<120, 256, 0, stream>>>(accD, inv, bc, wp, bp, out, N_NODES, i8ok ? 1 : 0);
}